// Round 12
// baseline (193.201 us; speedup 1.0000x reference)
//
#include <hip/hip_runtime.h>

#define NN 512
#define SCALE 0.35355339059327373f  /* dk^-0.5, dk=8 */
#define SMAX 6.0f                   /* fixed softmax shift (exact ratios) */

typedef short bf16x8 __attribute__((ext_vector_type(8)));
typedef float f32x4 __attribute__((ext_vector_type(4)));

__device__ __forceinline__ unsigned short bhi16(float x) {
    return (unsigned short)(__float_as_uint(x) >> 16);
}
__device__ __forceinline__ float btrunc(float x) {
    return __uint_as_float(__float_as_uint(x) & 0xFFFF0000u);
}
__device__ __forceinline__ unsigned short blo16(float x) {
    return (unsigned short)(__float_as_uint(x - btrunc(x)) >> 16);
}

// ---------------- K1: QKV projection ----------------
__global__ __launch_bounds__(64) void qkv_proj(const float* __restrict__ nin,
                                               const float* __restrict__ Wqkv,
                                               float* __restrict__ qkv) {
    const int r = blockIdx.x;
    const int j = threadIdx.x;
    const float* nr = nin + (size_t)r * 64;
    float a0 = 0.f, a1 = 0.f, a2 = 0.f;
#pragma unroll
    for (int d = 0; d < 64; ++d) {
        const float nv = nr[d];
        const float* wr = Wqkv + d * 192;
        a0 = fmaf(nv, wr[j], a0);
        a1 = fmaf(nv, wr[64 + j], a1);
        a2 = fmaf(nv, wr[128 + j], a2);
    }
    float* o = qkv + (size_t)r * 192;
    o[j] = a0; o[64 + j] = a1; o[128 + j] = a2;
}

__device__ __forceinline__ void gload16(const float* g, float* l) {
    __builtin_amdgcn_global_load_lds(
        (const __attribute__((address_space(1))) unsigned int*)(g),
        (__attribute__((address_space(3))) unsigned int*)(l), 16, 0, 0);
}
#define WAITV(N) asm volatile("s_waitcnt vmcnt(" #N ")" ::: "memory")

// ---------------- K2: m-split fused chunk kernel ----------------
// grid 8192 = (bn, chunk of 128 m-rows). 4 waves; wave owns 32 rows = 2 slabs.
// No barriers/sched_barriers in the hot path; waves fully decoupled.
// Outputs: e_out chunk (direct), partial pv[8h][8k], partial dn/gs per chunk.
__global__ __launch_bounds__(256, 4) void edge_mfma4(
    const float* __restrict__ e,
    const float* __restrict__ qkv,
    const float* __restrict__ We,   // (64,8)
    const float* __restrict__ Wg,   // (64,8)
    const float* __restrict__ Oe,   // (8,64)
    float* __restrict__ e_out,
    float* __restrict__ pvw,        // (8192, 64)
    float* __restrict__ dngs)       // (8192, 16) : dn[8] | gs[8]
{
    __shared__ float ebuf[4][2][16][64];  // per-wave slab dbuf (32 KB)
    __shared__ float E_lds[4][32][8];     // per-wave E scores (4 KB)
    __shared__ float red[256];
    __shared__ float wdn[4][8], wgs[4][8];

    const int t = threadIdx.x, w = t >> 6, l = t & 63;
    const int a2 = l >> 4;      // k-block / D row-group
    const int m16 = l & 15;     // fragment col (head for D)
    const int bid = blockIdx.x;
    const int wg = (bid & 7) * 1024 + (bid >> 3);  // XCD-chunked (8192%8==0)
    const int bn = wg >> 2, chunk = wg & 3;
    const int b = bn >> 9;
    const int rowc = chunk * 128 + w * 32;         // wave's global m-row base
    const float* __restrict__ Q = qkv + (size_t)bn * 192;
    const float* __restrict__ ebase = e + (size_t)bn * 32768;
    float* __restrict__ eob = e_out + (size_t)bn * 32768;

    // ---- prologue: persistent B-fragments (proven r10/r11 mapping) ----
    bf16x8 WfB[4], WcB[2], QdB[2];
#pragma unroll
    for (int blk = 0; blk < 4; ++blk) {
#pragma unroll
        for (int jj = 0; jj < 4; ++jj) {
            const int d = blk * 16 + a2 * 4 + jj;
            const float wv = (m16 < 8) ? We[d * 8 + m16] : Wg[d * 8 + m16 - 8];
            const short h = (short)bhi16(wv);
            WfB[blk][2 * jj] = h;
            WfB[blk][2 * jj + 1] = h;
        }
    }
#pragma unroll
    for (int c = 0; c < 2; ++c) {
        const int head = c * 4 + a2;
#pragma unroll
        for (int j = 0; j < 8; ++j) {
            const int d = c * 32 + a2 * 8 + j;
            const float wv = (m16 < 8) ? We[d * 8 + m16] : Wg[d * 8 + m16 - 8];
            WcB[c][j] = (short)blo16(wv);
            QdB[c][j] = (m16 == head) ? (short)bhi16(Q[d]) : (short)0;
        }
    }
    float dn = 0.f, gs = 0.f;

#define STAGE(s) do {                                                            \
        _Pragma("unroll")                                                        \
        for (int i_ = 0; i_ < 4; ++i_) {                                         \
            const int lrow_ = i_ * 4 + (l >> 4);                                 \
            gload16(ebase + (size_t)(rowc + (s) * 16 + lrow_) * 64               \
                        + (((l & 15) ^ lrow_) * 4),                              \
                    &ebuf[w][(s) & 1][i_ * 4][0]);                               \
        } } while (0)

#define SLAB(s, PREF, WN) do {                                                   \
        float4 kq0, kq1, kq2, kq3;                                               \
        { const float* kp_ = qkv + (size_t)(b * NN + rowc + (s) * 16 + m16) * 192 \
                             + 64 + a2 * 8;                                      \
          kq0 = *(const float4*)(kp_);      kq1 = *(const float4*)(kp_ + 4);     \
          kq2 = *(const float4*)(kp_ + 32); kq3 = *(const float4*)(kp_ + 36); }  \
        if (PREF) STAGE((s) + 1);                                                \
        WAITV(WN);                                                               \
        f32x4 c1 = {0.f, 0.f, 0.f, 0.f}, c2 = {0.f, 0.f, 0.f, 0.f};             \
        _Pragma("unroll")                                                        \
        for (int blk = 0; blk < 4; ++blk) {                                      \
            const float4 ev = *(const float4*)&ebuf[w][(s) & 1][m16]             \
                                  [(((blk * 4 + a2) ^ m16) * 4)];                \
            bf16x8 af;                                                           \
            af[0] = (short)bhi16(ev.x); af[1] = (short)blo16(ev.x);              \
            af[2] = (short)bhi16(ev.y); af[3] = (short)blo16(ev.y);              \
            af[4] = (short)bhi16(ev.z); af[5] = (short)blo16(ev.z);              \
            af[6] = (short)bhi16(ev.w); af[7] = (short)blo16(ev.w);              \
            c1 = __builtin_amdgcn_mfma_f32_16x16x32_bf16(af, WfB[blk], c1, 0, 0, 0); \
        }                                                                        \
        _Pragma("unroll")                                                        \
        for (int c = 0; c < 2; ++c) {                                            \
            const int g0 = c * 8 + a2 * 2;                                       \
            const float4 e0 = *(const float4*)&ebuf[w][(s) & 1][m16][((g0 ^ m16) * 4)]; \
            const float4 e1 = *(const float4*)&ebuf[w][(s) & 1][m16][(((g0 + 1) ^ m16) * 4)]; \
            bf16x8 ac;                                                           \
            ac[0] = (short)bhi16(e0.x); ac[1] = (short)bhi16(e0.y);              \
            ac[2] = (short)bhi16(e0.z); ac[3] = (short)bhi16(e0.w);              \
            ac[4] = (short)bhi16(e1.x); ac[5] = (short)bhi16(e1.y);              \
            ac[6] = (short)bhi16(e1.z); ac[7] = (short)bhi16(e1.w);              \
            c1 = __builtin_amdgcn_mfma_f32_16x16x32_bf16(ac, WcB[c], c1, 0, 0, 0); \
            const float4 k0 = (c == 0) ? kq0 : kq2;                              \
            const float4 k1 = (c == 0) ? kq1 : kq3;                              \
            bf16x8 kf;                                                           \
            kf[0] = (short)bhi16(k0.x); kf[1] = (short)bhi16(k0.y);              \
            kf[2] = (short)bhi16(k0.z); kf[3] = (short)bhi16(k0.w);              \
            kf[4] = (short)bhi16(k1.x); kf[5] = (short)bhi16(k1.y);              \
            kf[6] = (short)bhi16(k1.z); kf[7] = (short)bhi16(k1.w);              \
            c2 = __builtin_amdgcn_mfma_f32_16x16x32_bf16(kf, QdB[c], c2, 0, 0, 0); \
        }                                                                        \
        if (m16 < 8) {                                                           \
            _Pragma("unroll")                                                    \
            for (int r = 0; r < 4; ++r) {                                        \
                const float E_ = fminf(fmaxf(c2[r] * SCALE, -5.f), 5.f) + c1[r]; \
                dn += __expf(E_ - SMAX);                                         \
                E_lds[w][(s) * 16 + a2 * 4 + r][m16] = E_;                       \
            }                                                                    \
        } else {                                                                 \
            _Pragma("unroll")                                                    \
            for (int r = 0; r < 4; ++r) gs += 1.f / (1.f + __expf(-c1[r]));      \
        } } while (0)

    STAGE(0);
    SLAB(0, 1, 4);
    SLAB(1, 0, 4);

    // ---- reduce dn/gs across a2-groups ----
    dn += __shfl_xor(dn, 16, 64); dn += __shfl_xor(dn, 32, 64);
    gs += __shfl_xor(gs, 16, 64); gs += __shfl_xor(gs, 32, 64);
    if (a2 == 0 && m16 < 8) wdn[w][m16] = dn;
    if (a2 == 0 && m16 >= 8) wgs[w][m16 - 8] = gs;

    // ---- PV partial over own-wave 32 rows (loads only, no stores in flight) --
    {
        const int k = l & 7, hh = (l >> 3) & 7;
        const float* vb = qkv + (size_t)(b * NN + rowc) * 192 + 128 + hh * 8 + k;
        float acc = 0.f;
#pragma unroll 8
        for (int i = 0; i < 32; ++i) {
            const float p = __expf(E_lds[w][i][hh] - SMAX);
            acc = fmaf(p, vb[(size_t)i * 192], acc);
        }
        red[t] = acc;
    }
    __syncthreads();
    if (t < 64)
        pvw[(size_t)wg * 64 + t] = red[t] + red[64 + t] + red[128 + t] + red[192 + t];
    if (t < 8)
        dngs[(size_t)wg * 16 + t] = wdn[0][t] + wdn[1][t] + wdn[2][t] + wdn[3][t];
    else if (t < 16)
        dngs[(size_t)wg * 16 + t] = wgs[0][t - 8] + wgs[1][t - 8] + wgs[2][t - 8] + wgs[3][t - 8];

    // ---- e_out epilogue from E_lds (pure stores; drain into next block) ----
    {
        const int j4 = l & 15, mr = l >> 4;
        float oc[8][4];
#pragma unroll
        for (int h = 0; h < 8; ++h) {
            const float4 v = reinterpret_cast<const float4*>(Oe + h * 64 + j4 * 4)[0];
            oc[h][0] = v.x; oc[h][1] = v.y; oc[h][2] = v.z; oc[h][3] = v.w;
        }
#pragma unroll 2
        for (int p = 0; p < 8; ++p) {
            const int mloc = p * 4 + mr;
            const float* er = &E_lds[w][mloc][0];
            const float4 ra = *reinterpret_cast<const float4*>(er);
            const float4 rb = *reinterpret_cast<const float4*>(er + 4);
            float o0 = ra.x * oc[0][0], o1 = ra.x * oc[0][1], o2 = ra.x * oc[0][2], o3 = ra.x * oc[0][3];
            o0 = fmaf(ra.y, oc[1][0], o0); o1 = fmaf(ra.y, oc[1][1], o1); o2 = fmaf(ra.y, oc[1][2], o2); o3 = fmaf(ra.y, oc[1][3], o3);
            o0 = fmaf(ra.z, oc[2][0], o0); o1 = fmaf(ra.z, oc[2][1], o1); o2 = fmaf(ra.z, oc[2][2], o2); o3 = fmaf(ra.z, oc[2][3], o3);
            o0 = fmaf(ra.w, oc[3][0], o0); o1 = fmaf(ra.w, oc[3][1], o1); o2 = fmaf(ra.w, oc[3][2], o2); o3 = fmaf(ra.w, oc[3][3], o3);
            o0 = fmaf(rb.x, oc[4][0], o0); o1 = fmaf(rb.x, oc[4][1], o1); o2 = fmaf(rb.x, oc[4][2], o2); o3 = fmaf(rb.x, oc[4][3], o3);
            o0 = fmaf(rb.y, oc[5][0], o0); o1 = fmaf(rb.y, oc[5][1], o1); o2 = fmaf(rb.y, oc[5][2], o2); o3 = fmaf(rb.y, oc[5][3], o3);
            o0 = fmaf(rb.z, oc[6][0], o0); o1 = fmaf(rb.z, oc[6][1], o1); o2 = fmaf(rb.z, oc[6][2], o2); o3 = fmaf(rb.z, oc[6][3], o3);
            o0 = fmaf(rb.w, oc[7][0], o0); o1 = fmaf(rb.w, oc[7][1], o1); o2 = fmaf(rb.w, oc[7][2], o2); o3 = fmaf(rb.w, oc[7][3], o3);
            reinterpret_cast<float4*>(eob + (size_t)(rowc + mloc) * 64 + j4 * 4)[0]
                = make_float4(o0, o1, o2, o3);
        }
    }
#undef STAGE
#undef SLAB
}

// ---------------- K3: combine partials -> n_out ----------------
__global__ __launch_bounds__(64) void nout_fin(
    const float* __restrict__ pvw,   // (8192,64)
    const float* __restrict__ dngs,  // (8192,16)
    const float* __restrict__ On,    // (64,64)
    float* __restrict__ n_out)       // (B,N,64)
{
    __shared__ float vfin[64];
    const int bn = blockIdx.x, t = threadIdx.x;
    const int hh = t >> 3;
    float pv = 0.f, den = 0.f, gsum = 0.f;
#pragma unroll
    for (int c = 0; c < 4; ++c) {
        const size_t wg = (size_t)bn * 4 + c;
        pv += pvw[wg * 64 + t];
        den += dngs[wg * 16 + hh];
        gsum += dngs[wg * 16 + 8 + hh];
    }
    vfin[t] = pv * (1.f / den) * log1pf(gsum);
    __syncthreads();
    float acc = 0.f;
#pragma unroll
    for (int i = 0; i < 64; ++i)
        acc = fmaf(vfin[i], On[i * 64 + t], acc);
    n_out[(size_t)bn * 64 + t] = acc;
}

extern "C" void kernel_launch(void* const* d_in, const int* in_sizes, int n_in,
                              void* d_out, int out_size, void* d_ws, size_t ws_size,
                              hipStream_t stream) {
    const float* n_in_p = (const float*)d_in[0];
    const float* e_p    = (const float*)d_in[1];
    const float* Wqkv   = (const float*)d_in[2];
    const float* On     = (const float*)d_in[3];
    const float* Wg     = (const float*)d_in[4];
    const float* We     = (const float*)d_in[5];
    const float* Oe     = (const float*)d_in[6];
    float* out = (float*)d_out;
    float* n_out = out;                              // 4*512*64
    float* e_out = out + (size_t)4 * 512 * 64;       // 4*512*512*64
    float* qkv = (float*)d_ws;                       // 393216 floats
    float* pvw = qkv + 393216;                       // 524288 floats
    float* dngs = pvw + 524288;                      // 131072 floats

    hipLaunchKernelGGL(qkv_proj, dim3(4 * NN), dim3(64), 0, stream, n_in_p, Wqkv, qkv);
    hipLaunchKernelGGL(edge_mfma4, dim3(8192), dim3(256), 0, stream,
                       e_p, qkv, We, Wg, Oe, e_out, pvw, dngs);
    hipLaunchKernelGGL(nout_fin, dim3(4 * NN), dim3(64), 0, stream,
                       pvw, dngs, On, n_out);
}

// Round 13
// 175.963 us; speedup vs baseline: 1.0980x; 1.0980x over previous
//
#include <hip/hip_runtime.h>

#define NN 512
#define SCALE 0.35355339059327373f  /* dk^-0.5, dk=8 */
#define SMAX 6.0f                   /* fixed softmax shift (exact ratios) */

typedef short bf16x8 __attribute__((ext_vector_type(8)));
typedef float f32x4 __attribute__((ext_vector_type(4)));

static __device__ __forceinline__ unsigned short bhi16(float x) {
    return (unsigned short)(__float_as_uint(x) >> 16);
}
static __device__ __forceinline__ float btrunc(float x) {
    return __uint_as_float(__float_as_uint(x) & 0xFFFF0000u);
}
static __device__ __forceinline__ unsigned short blo16(float x) {
    return (unsigned short)(__float_as_uint(x - btrunc(x)) >> 16);
}

// ---------------- K1: QKV projection (+ K pre-truncated to bf16) ----------
__global__ __launch_bounds__(64) void qkv_proj(const float* __restrict__ nin,
                                               const float* __restrict__ Wqkv,
                                               float* __restrict__ qkv,
                                               unsigned short* __restrict__ kbf) {
    const int r = blockIdx.x;
    const int j = threadIdx.x;
    const float* nr = nin + (size_t)r * 64;
    float a0 = 0.f, a1 = 0.f, a2 = 0.f;
#pragma unroll
    for (int d = 0; d < 64; ++d) {
        const float nv = nr[d];
        const float* wr = Wqkv + d * 192;
        a0 = fmaf(nv, wr[j], a0);
        a1 = fmaf(nv, wr[64 + j], a1);
        a2 = fmaf(nv, wr[128 + j], a2);
    }
    float* o = qkv + (size_t)r * 192;
    o[j] = a0; o[64 + j] = a1; o[128 + j] = a2;
    kbf[(size_t)r * 64 + j] = bhi16(a1);   // same truncation the MFMA path used
}

__device__ __forceinline__ void gload16f(const float* g, float* l) {
    __builtin_amdgcn_global_load_lds(
        (const __attribute__((address_space(1))) unsigned int*)(g),
        (__attribute__((address_space(3))) unsigned int*)(l), 16, 0, 0);
}
__device__ __forceinline__ void gload16u(const unsigned short* g, unsigned short* l) {
    __builtin_amdgcn_global_load_lds(
        (const __attribute__((address_space(1))) unsigned int*)(g),
        (__attribute__((address_space(3))) unsigned int*)(l), 16, 0, 0);
}
#define WAITV(N) asm volatile("s_waitcnt vmcnt(" #N ")" ::: "memory")
#define BARRIER() __builtin_amdgcn_s_barrier()

// ---------------- K2: scatter-free fused chunk kernel ----------------
// grid 8192 = (bn, chunk of 128 m-rows). 4 waves; wave owns 32 rows = 2 slabs.
// ALL VMEM is full-line: e/K staged via gload16 (swizzled source), weights/Q/Oe
// staged to LDS once; fragments built from ds_reads (no TA scatter).
__global__ __launch_bounds__(256, 2) void edge_mfma5(
    const float* __restrict__ e,
    const float* __restrict__ qkv,
    const unsigned short* __restrict__ kbf,
    const float* __restrict__ We,   // (64,8)
    const float* __restrict__ Wg,   // (64,8)
    const float* __restrict__ Oe,   // (8,64)
    float* __restrict__ e_out,
    float* __restrict__ pvw,        // (8192, 64)
    float* __restrict__ dngs)       // (8192, 16)
{
    __shared__ float ebuf[4][2][16][64];          // 32 KB, per-wave slabs
    __shared__ unsigned short kbl[4][2][16][64];  // 16 KB, K bf16 slabs
    __shared__ float Wl[1024];                    // 4 KB  We | Wg
    __shared__ float Qlds[64];
    __shared__ float Oelds[512];                  // 2 KB
    __shared__ float E_lds[4][32][8];             // 4 KB
    __shared__ float red[256];
    __shared__ float wdn[4][8], wgs[4][8];

    const int t = threadIdx.x, w = t >> 6, l = t & 63;
    const int a2 = l >> 4, m16 = l & 15;
    const int bid = blockIdx.x;
    const int wg = (bid & 7) * 1024 + (bid >> 3);  // XCD-chunked (8192%8==0)
    const int bn = wg >> 2, chunk = wg & 3;
    const int b = bn >> 9;
    const int rowc = chunk * 128 + w * 32;
    const float* __restrict__ Qp = qkv + (size_t)bn * 192;
    const float* __restrict__ ebase = e + (size_t)bn * 32768;
    float* __restrict__ eob = e_out + (size_t)bn * 32768;

    // ---- issue ALL staging up front (15 full-line VMEM ops, fixed order) ----
    {
        const float* wsrc = (w < 2) ? (We + w * 256) : (Wg + (w - 2) * 256);
        gload16f(wsrc + l * 4, &Wl[w * 256]);                     // 1: weights qtr
        if (l < 16) gload16f(Qp + l * 4, &Qlds[0]);               // 2: Q (dup x4)
        if (l < 32) gload16f(Oe + w * 128 + l * 4, &Oelds[w * 128]); // 3: Oe qtr
    }
#pragma unroll
    for (int s = 0; s < 2; ++s) {
#pragma unroll
        for (int i_ = 0; i_ < 4; ++i_) {                          // e: 4/slab
            const int lrow = i_ * 4 + (l >> 4);
            gload16f(ebase + (size_t)(rowc + s * 16 + lrow) * 64 + (((l & 15) ^ lrow) * 4),
                     &ebuf[w][s][i_ * 4][0]);
        }
#pragma unroll
        for (int i_ = 0; i_ < 2; ++i_) {                          // K: 2/slab
            const int r8 = i_ * 8 + (l >> 3);
            gload16u(kbf + (size_t)(b * NN + rowc + s * 16 + r8) * 64 + (((l & 7) ^ (r8 & 7)) * 8),
                     &kbl[w][s][i_ * 8][0]);
        }
    }

    WAITV(12);       // retires weights/Q/Oe (3 oldest); e+K stay in flight
    BARRIER();

    // ---- persistent B-fragments from LDS (zero TA traffic) ----
    const int colbase = (m16 < 8) ? m16 : (504 + m16);  // Wg block at Wl[512+]
    bf16x8 WfB[4], WcB[2], QdB[2];
#pragma unroll
    for (int blk = 0; blk < 4; ++blk) {
#pragma unroll
        for (int jj = 0; jj < 4; ++jj) {
            const int d = blk * 16 + a2 * 4 + jj;
            const short h = (short)bhi16(Wl[d * 8 + colbase]);
            WfB[blk][2 * jj] = h;
            WfB[blk][2 * jj + 1] = h;
        }
    }
#pragma unroll
    for (int c = 0; c < 2; ++c) {
        const int head = c * 4 + a2;
#pragma unroll
        for (int j = 0; j < 8; ++j) {
            const int d = c * 32 + a2 * 8 + j;
            WcB[c][j] = (short)blo16(Wl[d * 8 + colbase]);
            QdB[c][j] = (m16 == head) ? (short)bhi16(Qlds[d]) : (short)0;
        }
    }
    float dn = 0.f, gs = 0.f;

#define SLAB(s, WN) do {                                                         \
        WAITV(WN);                                                               \
        f32x4 c1 = {0.f, 0.f, 0.f, 0.f}, c2 = {0.f, 0.f, 0.f, 0.f};             \
        _Pragma("unroll")                                                        \
        for (int blk = 0; blk < 4; ++blk) {                                      \
            const float4 ev = *(const float4*)&ebuf[w][s][m16]                   \
                                  [(((blk * 4 + a2) ^ m16) * 4)];                \
            bf16x8 af;                                                           \
            af[0] = (short)bhi16(ev.x); af[1] = (short)blo16(ev.x);              \
            af[2] = (short)bhi16(ev.y); af[3] = (short)blo16(ev.y);              \
            af[4] = (short)bhi16(ev.z); af[5] = (short)blo16(ev.z);              \
            af[6] = (short)bhi16(ev.w); af[7] = (short)blo16(ev.w);              \
            c1 = __builtin_amdgcn_mfma_f32_16x16x32_bf16(af, WfB[blk], c1, 0, 0, 0); \
        }                                                                        \
        _Pragma("unroll")                                                        \
        for (int c = 0; c < 2; ++c) {                                            \
            const int g0 = c * 8 + a2 * 2;                                       \
            const float4 e0 = *(const float4*)&ebuf[w][s][m16][((g0 ^ m16) * 4)]; \
            const float4 e1 = *(const float4*)&ebuf[w][s][m16][(((g0 + 1) ^ m16) * 4)]; \
            bf16x8 ac;                                                           \
            ac[0] = (short)bhi16(e0.x); ac[1] = (short)bhi16(e0.y);              \
            ac[2] = (short)bhi16(e0.z); ac[3] = (short)bhi16(e0.w);              \
            ac[4] = (short)bhi16(e1.x); ac[5] = (short)bhi16(e1.y);              \
            ac[6] = (short)bhi16(e1.z); ac[7] = (short)bhi16(e1.w);              \
            c1 = __builtin_amdgcn_mfma_f32_16x16x32_bf16(ac, WcB[c], c1, 0, 0, 0); \
            const bf16x8 kf = *(const bf16x8*)&kbl[w][s][m16]                    \
                                  [(((c * 4 + a2) ^ (m16 & 7)) * 8)];            \
            c2 = __builtin_amdgcn_mfma_f32_16x16x32_bf16(kf, QdB[c], c2, 0, 0, 0); \
        }                                                                        \
        if (m16 < 8) {                                                           \
            _Pragma("unroll")                                                    \
            for (int r = 0; r < 4; ++r) {                                        \
                const float E_ = fminf(fmaxf(c2[r] * SCALE, -5.f), 5.f) + c1[r]; \
                dn += __expf(E_ - SMAX);                                         \
                E_lds[w][(s) * 16 + a2 * 4 + r][m16] = E_;                       \
            }                                                                    \
        } else {                                                                 \
            _Pragma("unroll")                                                    \
            for (int r = 0; r < 4; ++r) gs += 1.f / (1.f + __expf(-c1[r]));      \
        } } while (0)

    SLAB(0, 6);      // e0+K0 retired; e1+K1 (6) stay in flight
    SLAB(1, 0);

    // ---- reduce dn/gs across a2-groups ----
    dn += __shfl_xor(dn, 16, 64); dn += __shfl_xor(dn, 32, 64);
    gs += __shfl_xor(gs, 16, 64); gs += __shfl_xor(gs, 32, 64);
    if (a2 == 0 && m16 < 8) wdn[w][m16] = dn;
    if (a2 == 0 && m16 >= 8) wgs[w][m16 - 8] = gs;

    // ---- PV partial over own-wave 32 rows (contiguous 256B/instr, L2-hot) ----
    {
        const int k = l & 7, hh = (l >> 3) & 7;
        const float* vb = qkv + (size_t)(b * NN + rowc) * 192 + 128 + hh * 8 + k;
        float acc = 0.f;
#pragma unroll 8
        for (int i = 0; i < 32; ++i) {
            const float p = __expf(E_lds[w][i][hh] - SMAX);
            acc = fmaf(p, vb[(size_t)i * 192], acc);
        }
        red[t] = acc;
    }
    __syncthreads();
    if (t < 64)
        pvw[(size_t)wg * 64 + t] = red[t] + red[64 + t] + red[128 + t] + red[192 + t];
    if (t < 8)
        dngs[(size_t)wg * 16 + t] = wdn[0][t] + wdn[1][t] + wdn[2][t] + wdn[3][t];
    else if (t < 16)
        dngs[(size_t)wg * 16 + t] = wgs[0][t - 8] + wgs[1][t - 8] + wgs[2][t - 8] + wgs[3][t - 8];

    // ---- e_out epilogue from E_lds; Oe coefficients from LDS ----
    {
        const int j4 = l & 15, mr = l >> 4;
        float oc[8][4];
#pragma unroll
        for (int h = 0; h < 8; ++h) {
            const float4 v = *(const float4*)&Oelds[h * 64 + j4 * 4];
            oc[h][0] = v.x; oc[h][1] = v.y; oc[h][2] = v.z; oc[h][3] = v.w;
        }
#pragma unroll 2
        for (int p = 0; p < 8; ++p) {
            const int mloc = p * 4 + mr;
            const float* er = &E_lds[w][mloc][0];
            const float4 ra = *reinterpret_cast<const float4*>(er);
            const float4 rb = *reinterpret_cast<const float4*>(er + 4);
            float o0 = ra.x * oc[0][0], o1 = ra.x * oc[0][1], o2 = ra.x * oc[0][2], o3 = ra.x * oc[0][3];
            o0 = fmaf(ra.y, oc[1][0], o0); o1 = fmaf(ra.y, oc[1][1], o1); o2 = fmaf(ra.y, oc[1][2], o2); o3 = fmaf(ra.y, oc[1][3], o3);
            o0 = fmaf(ra.z, oc[2][0], o0); o1 = fmaf(ra.z, oc[2][1], o1); o2 = fmaf(ra.z, oc[2][2], o2); o3 = fmaf(ra.z, oc[2][3], o3);
            o0 = fmaf(ra.w, oc[3][0], o0); o1 = fmaf(ra.w, oc[3][1], o1); o2 = fmaf(ra.w, oc[3][2], o2); o3 = fmaf(ra.w, oc[3][3], o3);
            o0 = fmaf(rb.x, oc[4][0], o0); o1 = fmaf(rb.x, oc[4][1], o1); o2 = fmaf(rb.x, oc[4][2], o2); o3 = fmaf(rb.x, oc[4][3], o3);
            o0 = fmaf(rb.y, oc[5][0], o0); o1 = fmaf(rb.y, oc[5][1], o1); o2 = fmaf(rb.y, oc[5][2], o2); o3 = fmaf(rb.y, oc[5][3], o3);
            o0 = fmaf(rb.z, oc[6][0], o0); o1 = fmaf(rb.z, oc[6][1], o1); o2 = fmaf(rb.z, oc[6][2], o2); o3 = fmaf(rb.z, oc[6][3], o3);
            o0 = fmaf(rb.w, oc[7][0], o0); o1 = fmaf(rb.w, oc[7][1], o1); o2 = fmaf(rb.w, oc[7][2], o2); o3 = fmaf(rb.w, oc[7][3], o3);
            reinterpret_cast<float4*>(eob + (size_t)(rowc + mloc) * 64 + j4 * 4)[0]
                = make_float4(o0, o1, o2, o3);
        }
    }
#undef SLAB
}

// ---------------- K3: combine partials -> n_out ----------------
__global__ __launch_bounds__(64) void nout_fin(
    const float* __restrict__ pvw,   // (8192,64)
    const float* __restrict__ dngs,  // (8192,16)
    const float* __restrict__ On,    // (64,64)
    float* __restrict__ n_out)       // (B,N,64)
{
    __shared__ float vfin[64];
    const int bn = blockIdx.x, t = threadIdx.x;
    const int hh = t >> 3;
    float pv = 0.f, den = 0.f, gsum = 0.f;
#pragma unroll
    for (int c = 0; c < 4; ++c) {
        const size_t wg = (size_t)bn * 4 + c;
        pv += pvw[wg * 64 + t];
        den += dngs[wg * 16 + hh];
        gsum += dngs[wg * 16 + 8 + hh];
    }
    vfin[t] = pv * (1.f / den) * log1pf(gsum);
    __syncthreads();
    float acc = 0.f;
#pragma unroll
    for (int i = 0; i < 64; ++i)
        acc = fmaf(vfin[i], On[i * 64 + t], acc);
    n_out[(size_t)bn * 64 + t] = acc;
}

extern "C" void kernel_launch(void* const* d_in, const int* in_sizes, int n_in,
                              void* d_out, int out_size, void* d_ws, size_t ws_size,
                              hipStream_t stream) {
    const float* n_in_p = (const float*)d_in[0];
    const float* e_p    = (const float*)d_in[1];
    const float* Wqkv   = (const float*)d_in[2];
    const float* On     = (const float*)d_in[3];
    const float* Wg     = (const float*)d_in[4];
    const float* We     = (const float*)d_in[5];
    const float* Oe     = (const float*)d_in[6];
    float* out = (float*)d_out;
    float* n_out = out;                              // 4*512*64
    float* e_out = out + (size_t)4 * 512 * 64;       // 4*512*512*64
    float* qkv = (float*)d_ws;                       // 393216 floats
    float* pvw = qkv + 393216;                       // 524288 floats
    float* dngs = pvw + 524288;                      // 131072 floats
    unsigned short* kbf = (unsigned short*)(dngs + 131072);  // 131072 ushorts

    hipLaunchKernelGGL(qkv_proj, dim3(4 * NN), dim3(64), 0, stream, n_in_p, Wqkv, qkv, kbf);
    hipLaunchKernelGGL(edge_mfma5, dim3(8192), dim3(256), 0, stream,
                       e_p, qkv, kbf, We, Wg, Oe, e_out, pvw, dngs);
    hipLaunchKernelGGL(nout_fin, dim3(4 * NN), dim3(64), 0, stream,
                       pvw, dngs, On, n_out);
}

// Round 14
// 158.063 us; speedup vs baseline: 1.2223x; 1.1132x over previous
//
#include <hip/hip_runtime.h>

#define NN 512
#define SCALE 0.35355339059327373f  /* dk^-0.5, dk=8 */
#define SMAX 6.0f                   /* fixed softmax shift (exact ratios) */

typedef short bf16x8 __attribute__((ext_vector_type(8)));
typedef float f32x4 __attribute__((ext_vector_type(4)));

static __device__ __forceinline__ unsigned short bhi16(float x) {
    return (unsigned short)(__float_as_uint(x) >> 16);
}
static __device__ __forceinline__ float btrunc(float x) {
    return __uint_as_float(__float_as_uint(x) & 0xFFFF0000u);
}
static __device__ __forceinline__ unsigned short blo16(float x) {
    return (unsigned short)(__float_as_uint(x - btrunc(x)) >> 16);
}

// ---------------- K1: QKV projection (+ K pre-truncated to bf16) ----------
__global__ __launch_bounds__(64) void qkv_proj(const float* __restrict__ nin,
                                               const float* __restrict__ Wqkv,
                                               float* __restrict__ qkv,
                                               unsigned short* __restrict__ kbf) {
    const int r = blockIdx.x;
    const int j = threadIdx.x;
    const float* nr = nin + (size_t)r * 64;
    float a0 = 0.f, a1 = 0.f, a2 = 0.f;
#pragma unroll
    for (int d = 0; d < 64; ++d) {
        const float nv = nr[d];
        const float* wr = Wqkv + d * 192;
        a0 = fmaf(nv, wr[j], a0);
        a1 = fmaf(nv, wr[64 + j], a1);
        a2 = fmaf(nv, wr[128 + j], a2);
    }
    float* o = qkv + (size_t)r * 192;
    o[j] = a0; o[64 + j] = a1; o[128 + j] = a2;
    kbf[(size_t)r * 64 + j] = bhi16(a1);
}

__device__ __forceinline__ void gload16f(const float* g, float* l) {
    __builtin_amdgcn_global_load_lds(
        (const __attribute__((address_space(1))) unsigned int*)(g),
        (__attribute__((address_space(3))) unsigned int*)(l), 16, 0, 0);
}
__device__ __forceinline__ void gload16u(const unsigned short* g, unsigned short* l) {
    __builtin_amdgcn_global_load_lds(
        (const __attribute__((address_space(1))) unsigned int*)(g),
        (__attribute__((address_space(3))) unsigned int*)(l), 16, 0, 0);
}
#define WAITV(N) asm volatile("s_waitcnt vmcnt(" #N ")" ::: "memory")
#define BARRIER() __builtin_amdgcn_s_barrier()

// ---------------- K2: scatter-free, 4-blocks/CU fused chunk kernel ---------
// grid 8192 = (bn, chunk of 128 m-rows). 4 waves; wave owns 32 rows = 2 slabs,
// SINGLE-buffered (stage slab1 after slab0 compute) -> LDS 35.5 KB, 4 blk/CU.
// Cross-block TLP (16 waves/CU, staggered phases) hides the staging latency.
__global__ __launch_bounds__(256, 4) void edge_mfma6(
    const float* __restrict__ e,
    const float* __restrict__ qkv,
    const unsigned short* __restrict__ kbf,
    const float* __restrict__ We,   // (64,8)
    const float* __restrict__ Wg,   // (64,8)
    const float* __restrict__ Oe,   // (8,64)
    float* __restrict__ e_out,
    float* __restrict__ pvw,        // (8192, 64)
    float* __restrict__ dngs)       // (8192, 16)
{
    __shared__ float ebuf[4][16][64];             // 16 KB (single-buffered)
    __shared__ unsigned short kbl[4][16][64];     // 8 KB
    __shared__ float Wl[1024];                    // 4 KB  We | Wg
    __shared__ float Qlds[64];
    __shared__ float Oelds[512];                  // 2 KB
    __shared__ float E_lds[4][32][8];             // 4 KB
    __shared__ float red[256];
    __shared__ float wdn[4][8], wgs[4][8];

    const int t = threadIdx.x, w = t >> 6, l = t & 63;
    const int a2 = l >> 4, m16 = l & 15;
    const int bid = blockIdx.x;
    const int wg = (bid & 7) * 1024 + (bid >> 3);  // XCD-chunked (8192%8==0)
    const int bn = wg >> 2, chunk = wg & 3;
    const int b = bn >> 9;
    const int rowc = chunk * 128 + w * 32;
    const float* __restrict__ Qp = qkv + (size_t)bn * 192;
    const float* __restrict__ ebase = e + (size_t)bn * 32768;
    float* __restrict__ eob = e_out + (size_t)bn * 32768;

#define STAGE_E(s) do {                                                          \
        _Pragma("unroll")                                                        \
        for (int i_ = 0; i_ < 4; ++i_) {                                         \
            const int lrow = i_ * 4 + (l >> 4);                                  \
            gload16f(ebase + (size_t)(rowc + (s) * 16 + lrow) * 64 + (((l & 15) ^ lrow) * 4), \
                     &ebuf[w][i_ * 4][0]);                                       \
        } } while (0)
#define STAGE_K(s) do {                                                          \
        _Pragma("unroll")                                                        \
        for (int i_ = 0; i_ < 2; ++i_) {                                         \
            const int r8 = i_ * 8 + (l >> 3);                                    \
            gload16u(kbf + (size_t)(b * NN + rowc + (s) * 16 + r8) * 64 + (((l & 7) ^ (r8 & 7)) * 8), \
                     &kbl[w][i_ * 8][0]);                                        \
        } } while (0)

    // ---- issue shared staging (3) + slab0 (6); fixed order for counted waits
    {
        const float* wsrc = (w < 2) ? (We + w * 256) : (Wg + (w - 2) * 256);
        gload16f(wsrc + l * 4, &Wl[w * 256]);
        if (l < 16) gload16f(Qp + l * 4, &Qlds[0]);
        if (l < 32) gload16f(Oe + w * 128 + l * 4, &Oelds[w * 128]);
    }
    STAGE_E(0); STAGE_K(0);

    WAITV(6);        // retires the 3 shared loads; slab0 stays in flight
    BARRIER();

    // ---- persistent B-fragments from LDS (zero TA scatter) ----
    const int colbase = (m16 < 8) ? m16 : (504 + m16);
    bf16x8 WfB[4], WcB[2], QdB[2];
#pragma unroll
    for (int blk = 0; blk < 4; ++blk) {
#pragma unroll
        for (int jj = 0; jj < 4; ++jj) {
            const int d = blk * 16 + a2 * 4 + jj;
            const short h = (short)bhi16(Wl[d * 8 + colbase]);
            WfB[blk][2 * jj] = h;
            WfB[blk][2 * jj + 1] = h;
        }
    }
#pragma unroll
    for (int c = 0; c < 2; ++c) {
        const int head = c * 4 + a2;
#pragma unroll
        for (int j = 0; j < 8; ++j) {
            const int d = c * 32 + a2 * 8 + j;
            WcB[c][j] = (short)blo16(Wl[d * 8 + colbase]);
            QdB[c][j] = (m16 == head) ? (short)bhi16(Qlds[d]) : (short)0;
        }
    }
    float dn = 0.f, gs = 0.f;

#define SLAB(s) do {                                                             \
        f32x4 c1 = {0.f, 0.f, 0.f, 0.f}, c2 = {0.f, 0.f, 0.f, 0.f};             \
        _Pragma("unroll")                                                        \
        for (int blk = 0; blk < 4; ++blk) {                                      \
            const float4 ev = *(const float4*)&ebuf[w][m16]                      \
                                  [(((blk * 4 + a2) ^ m16) * 4)];                \
            bf16x8 af;                                                           \
            af[0] = (short)bhi16(ev.x); af[1] = (short)blo16(ev.x);              \
            af[2] = (short)bhi16(ev.y); af[3] = (short)blo16(ev.y);              \
            af[4] = (short)bhi16(ev.z); af[5] = (short)blo16(ev.z);              \
            af[6] = (short)bhi16(ev.w); af[7] = (short)blo16(ev.w);              \
            c1 = __builtin_amdgcn_mfma_f32_16x16x32_bf16(af, WfB[blk], c1, 0, 0, 0); \
        }                                                                        \
        _Pragma("unroll")                                                        \
        for (int c = 0; c < 2; ++c) {                                            \
            const int g0 = c * 8 + a2 * 2;                                       \
            const float4 e0 = *(const float4*)&ebuf[w][m16][((g0 ^ m16) * 4)];   \
            const float4 e1 = *(const float4*)&ebuf[w][m16][(((g0 + 1) ^ m16) * 4)]; \
            bf16x8 ac;                                                           \
            ac[0] = (short)bhi16(e0.x); ac[1] = (short)bhi16(e0.y);              \
            ac[2] = (short)bhi16(e0.z); ac[3] = (short)bhi16(e0.w);              \
            ac[4] = (short)bhi16(e1.x); ac[5] = (short)bhi16(e1.y);              \
            ac[6] = (short)bhi16(e1.z); ac[7] = (short)bhi16(e1.w);              \
            c1 = __builtin_amdgcn_mfma_f32_16x16x32_bf16(ac, WcB[c], c1, 0, 0, 0); \
            const bf16x8 kf = *(const bf16x8*)&kbl[w][m16]                       \
                                  [(((c * 4 + a2) ^ (m16 & 7)) * 8)];            \
            c2 = __builtin_amdgcn_mfma_f32_16x16x32_bf16(kf, QdB[c], c2, 0, 0, 0); \
        }                                                                        \
        if (m16 < 8) {                                                           \
            _Pragma("unroll")                                                    \
            for (int r = 0; r < 4; ++r) {                                        \
                const float E_ = fminf(fmaxf(c2[r] * SCALE, -5.f), 5.f) + c1[r]; \
                dn += __expf(E_ - SMAX);                                         \
                E_lds[w][(s) * 16 + a2 * 4 + r][m16] = E_;                       \
            }                                                                    \
        } else {                                                                 \
            _Pragma("unroll")                                                    \
            for (int r = 0; r < 4; ++r) gs += 1.f / (1.f + __expf(-c1[r]));      \
        } } while (0)

    WAITV(0);        // slab0 e+K landed
    SLAB(0);
    STAGE_E(1); STAGE_K(1);       // single buffer: reissue after slab0 reads
    WAITV(0);
    SLAB(1);

    // ---- reduce dn/gs across a2-groups ----
    dn += __shfl_xor(dn, 16, 64); dn += __shfl_xor(dn, 32, 64);
    gs += __shfl_xor(gs, 16, 64); gs += __shfl_xor(gs, 32, 64);
    if (a2 == 0 && m16 < 8) wdn[w][m16] = dn;
    if (a2 == 0 && m16 >= 8) wgs[w][m16 - 8] = gs;

    // ---- PV partial over own-wave 32 rows (256B/instr, L2-hot) ----
    {
        const int k = l & 7, hh = (l >> 3) & 7;
        const float* vb = qkv + (size_t)(b * NN + rowc) * 192 + 128 + hh * 8 + k;
        float acc = 0.f;
#pragma unroll 8
        for (int i = 0; i < 32; ++i) {
            const float p = __expf(E_lds[w][i][hh] - SMAX);
            acc = fmaf(p, vb[(size_t)i * 192], acc);
        }
        red[t] = acc;
    }
    __syncthreads();
    if (t < 64)
        pvw[(size_t)wg * 64 + t] = red[t] + red[64 + t] + red[128 + t] + red[192 + t];
    if (t < 8)
        dngs[(size_t)wg * 16 + t] = wdn[0][t] + wdn[1][t] + wdn[2][t] + wdn[3][t];
    else if (t < 16)
        dngs[(size_t)wg * 16 + t] = wgs[0][t - 8] + wgs[1][t - 8] + wgs[2][t - 8] + wgs[3][t - 8];

    // ---- e_out epilogue from E_lds; Oe coefficients from LDS ----
    {
        const int j4 = l & 15, mr = l >> 4;
        float oc[8][4];
#pragma unroll
        for (int h = 0; h < 8; ++h) {
            const float4 v = *(const float4*)&Oelds[h * 64 + j4 * 4];
            oc[h][0] = v.x; oc[h][1] = v.y; oc[h][2] = v.z; oc[h][3] = v.w;
        }
#pragma unroll 2
        for (int p = 0; p < 8; ++p) {
            const int mloc = p * 4 + mr;
            const float* er = &E_lds[w][mloc][0];
            const float4 ra = *reinterpret_cast<const float4*>(er);
            const float4 rb = *reinterpret_cast<const float4*>(er + 4);
            float o0 = ra.x * oc[0][0], o1 = ra.x * oc[0][1], o2 = ra.x * oc[0][2], o3 = ra.x * oc[0][3];
            o0 = fmaf(ra.y, oc[1][0], o0); o1 = fmaf(ra.y, oc[1][1], o1); o2 = fmaf(ra.y, oc[1][2], o2); o3 = fmaf(ra.y, oc[1][3], o3);
            o0 = fmaf(ra.z, oc[2][0], o0); o1 = fmaf(ra.z, oc[2][1], o1); o2 = fmaf(ra.z, oc[2][2], o2); o3 = fmaf(ra.z, oc[2][3], o3);
            o0 = fmaf(ra.w, oc[3][0], o0); o1 = fmaf(ra.w, oc[3][1], o1); o2 = fmaf(ra.w, oc[3][2], o2); o3 = fmaf(ra.w, oc[3][3], o3);
            o0 = fmaf(rb.x, oc[4][0], o0); o1 = fmaf(rb.x, oc[4][1], o1); o2 = fmaf(rb.x, oc[4][2], o2); o3 = fmaf(rb.x, oc[4][3], o3);
            o0 = fmaf(rb.y, oc[5][0], o0); o1 = fmaf(rb.y, oc[5][1], o1); o2 = fmaf(rb.y, oc[5][2], o2); o3 = fmaf(rb.y, oc[5][3], o3);
            o0 = fmaf(rb.z, oc[6][0], o0); o1 = fmaf(rb.z, oc[6][1], o1); o2 = fmaf(rb.z, oc[6][2], o2); o3 = fmaf(rb.z, oc[6][3], o3);
            o0 = fmaf(rb.w, oc[7][0], o0); o1 = fmaf(rb.w, oc[7][1], o1); o2 = fmaf(rb.w, oc[7][2], o2); o3 = fmaf(rb.w, oc[7][3], o3);
            reinterpret_cast<float4*>(eob + (size_t)(rowc + mloc) * 64 + j4 * 4)[0]
                = make_float4(o0, o1, o2, o3);
        }
    }
#undef STAGE_E
#undef STAGE_K
#undef SLAB
}

// ---------------- K3: combine partials -> n_out ----------------
__global__ __launch_bounds__(64) void nout_fin(
    const float* __restrict__ pvw,   // (8192,64)
    const float* __restrict__ dngs,  // (8192,16)
    const float* __restrict__ On,    // (64,64)
    float* __restrict__ n_out)       // (B,N,64)
{
    __shared__ float vfin[64];
    const int bn = blockIdx.x, t = threadIdx.x;
    const int hh = t >> 3;
    float pv = 0.f, den = 0.f, gsum = 0.f;
#pragma unroll
    for (int c = 0; c < 4; ++c) {
        const size_t wg = (size_t)bn * 4 + c;
        pv += pvw[wg * 64 + t];
        den += dngs[wg * 16 + hh];
        gsum += dngs[wg * 16 + 8 + hh];
    }
    vfin[t] = pv * (1.f / den) * log1pf(gsum);
    __syncthreads();
    float acc = 0.f;
#pragma unroll
    for (int i = 0; i < 64; ++i)
        acc = fmaf(vfin[i], On[i * 64 + t], acc);
    n_out[(size_t)bn * 64 + t] = acc;
}

extern "C" void kernel_launch(void* const* d_in, const int* in_sizes, int n_in,
                              void* d_out, int out_size, void* d_ws, size_t ws_size,
                              hipStream_t stream) {
    const float* n_in_p = (const float*)d_in[0];
    const float* e_p    = (const float*)d_in[1];
    const float* Wqkv   = (const float*)d_in[2];
    const float* On     = (const float*)d_in[3];
    const float* Wg     = (const float*)d_in[4];
    const float* We     = (const float*)d_in[5];
    const float* Oe     = (const float*)d_in[6];
    float* out = (float*)d_out;
    float* n_out = out;                              // 4*512*64
    float* e_out = out + (size_t)4 * 512 * 64;       // 4*512*512*64
    float* qkv = (float*)d_ws;                       // 393216 floats
    float* pvw = qkv + 393216;                       // 524288 floats
    float* dngs = pvw + 524288;                      // 131072 floats
    unsigned short* kbf = (unsigned short*)(dngs + 131072);  // 131072 ushorts

    hipLaunchKernelGGL(qkv_proj, dim3(4 * NN), dim3(64), 0, stream, n_in_p, Wqkv, qkv, kbf);
    hipLaunchKernelGGL(edge_mfma6, dim3(8192), dim3(256), 0, stream,
                       e_p, qkv, kbf, We, Wg, Oe, e_out, pvw, dngs);
    hipLaunchKernelGGL(nout_fin, dim3(4 * NN), dim3(64), 0, stream,
                       pvw, dngs, On, n_out);
}

// Round 15
// 154.209 us; speedup vs baseline: 1.2529x; 1.0250x over previous
//
#include <hip/hip_runtime.h>

#define NN 512
#define SCALE 0.35355339059327373f  /* dk^-0.5, dk=8 */
#define SMAX 6.0f                   /* fixed softmax shift (exact ratios) */

typedef short bf16x8 __attribute__((ext_vector_type(8)));
typedef float f32x4 __attribute__((ext_vector_type(4)));

static __device__ __forceinline__ unsigned short bhi16(float x) {
    return (unsigned short)(__float_as_uint(x) >> 16);
}

// ---------------- K1: QKV projection (+ K pre-truncated to bf16) ----------
__global__ __launch_bounds__(64) void qkv_proj(const float* __restrict__ nin,
                                               const float* __restrict__ Wqkv,
                                               float* __restrict__ qkv,
                                               unsigned short* __restrict__ kbf) {
    const int r = blockIdx.x;
    const int j = threadIdx.x;
    const float* nr = nin + (size_t)r * 64;
    float a0 = 0.f, a1 = 0.f, a2 = 0.f;
#pragma unroll
    for (int d = 0; d < 64; ++d) {
        const float nv = nr[d];
        const float* wr = Wqkv + d * 192;
        a0 = fmaf(nv, wr[j], a0);
        a1 = fmaf(nv, wr[64 + j], a1);
        a2 = fmaf(nv, wr[128 + j], a2);
    }
    float* o = qkv + (size_t)r * 192;
    o[j] = a0; o[64 + j] = a1; o[128 + j] = a2;
    kbf[(size_t)r * 64 + j] = bhi16(a1);
}

__device__ __forceinline__ void gload16f(const float* g, float* l) {
    __builtin_amdgcn_global_load_lds(
        (const __attribute__((address_space(1))) unsigned int*)(g),
        (__attribute__((address_space(3))) unsigned int*)(l), 16, 0, 0);
}
__device__ __forceinline__ void gload16u(const unsigned short* g, unsigned short* l) {
    __builtin_amdgcn_global_load_lds(
        (const __attribute__((address_space(1))) unsigned int*)(g),
        (__attribute__((address_space(3))) unsigned int*)(l), 16, 0, 0);
}
#define WAITV(N) asm volatile("s_waitcnt vmcnt(" #N ")" ::: "memory")
#define BARRIER() __builtin_amdgcn_s_barrier()

// ---------------- K2: single-bf16, 5-blocks/CU fused chunk kernel ----------
// grid 8192 = (bn, chunk of 128 m-rows). 4 waves; wave owns 32 rows = 2 slabs,
// single-buffered. 4 MFMAs/slab (2 ee|gg + 2 QK). Wl/Q union'd with E_lds.
__global__ __launch_bounds__(256, 5) void edge_mfma7(
    const float* __restrict__ e,
    const float* __restrict__ qkv,
    const unsigned short* __restrict__ kbf,
    const float* __restrict__ We,   // (64,8)
    const float* __restrict__ Wg,   // (64,8)
    const float* __restrict__ Oe,   // (8,64)
    float* __restrict__ e_out,
    float* __restrict__ pvw,        // (8192, 64)
    float* __restrict__ dngs)       // (8192, 16)
{
    __shared__ float ebuf[4][16][64];             // 16 KB (single-buffered)
    __shared__ unsigned short kbl[4][16][64];     // 8 KB
    __shared__ float uni[1088];                   // Wl[1024]|Qlds[64] -> E_lds
    __shared__ float Oelds[512];                  // 2 KB
    __shared__ float red[256];                    // 1 KB
    __shared__ float wdn[4][8], wgs[4][8];

    float* const Wl = uni;
    float* const Qlds = uni + 1024;
    auto E_lds = reinterpret_cast<float(*)[32][8]>(uni);  // valid after barrier2

    const int t = threadIdx.x, w = t >> 6, l = t & 63;
    const int a2 = l >> 4, m16 = l & 15;
    const int bid = blockIdx.x;
    const int wg = (bid & 7) * 1024 + (bid >> 3);  // XCD-chunked (8192%8==0)
    const int bn = wg >> 2, chunk = wg & 3;
    const int b = bn >> 9;
    const int rowc = chunk * 128 + w * 32;
    const float* __restrict__ Qp = qkv + (size_t)bn * 192;
    const float* __restrict__ ebase = e + (size_t)bn * 32768;
    float* __restrict__ eob = e_out + (size_t)bn * 32768;

#define STAGE_E(s) do {                                                          \
        _Pragma("unroll")                                                        \
        for (int i_ = 0; i_ < 4; ++i_) {                                         \
            const int lrow = i_ * 4 + (l >> 4);                                  \
            gload16f(ebase + (size_t)(rowc + (s) * 16 + lrow) * 64 + (((l & 15) ^ lrow) * 4), \
                     &ebuf[w][i_ * 4][0]);                                       \
        } } while (0)
#define STAGE_K(s) do {                                                          \
        _Pragma("unroll")                                                        \
        for (int i_ = 0; i_ < 2; ++i_) {                                         \
            const int r8 = i_ * 8 + (l >> 3);                                    \
            gload16u(kbf + (size_t)(b * NN + rowc + (s) * 16 + r8) * 64 + (((l & 7) ^ (r8 & 7)) * 8), \
                     &kbl[w][i_ * 8][0]);                                        \
        } } while (0)

    // ---- issue shared staging (3) + slab0 (6); fixed order for counted waits
    {
        const float* wsrc = (w < 2) ? (We + w * 256) : (Wg + (w - 2) * 256);
        gload16f(wsrc + l * 4, &Wl[w * 256]);
        if (l < 16) gload16f(Qp + l * 4, &Qlds[0]);
        if (l < 32) gload16f(Oe + w * 128 + l * 4, &Oelds[w * 128]);
    }
    STAGE_E(0); STAGE_K(0);

    WAITV(6);        // retires the 3 shared loads; slab0 stays in flight
    BARRIER();

    // ---- persistent B-fragments from LDS (single-bf16: 4 fragments total) --
    const int colbase = (m16 < 8) ? m16 : (504 + m16);
    bf16x8 WB[2], QdB[2];
#pragma unroll
    for (int c = 0; c < 2; ++c) {
        const int head = c * 4 + a2;
#pragma unroll
        for (int j = 0; j < 8; ++j) {
            const int d = c * 32 + a2 * 8 + j;
            WB[c][j] = (short)bhi16(Wl[d * 8 + colbase]);
            QdB[c][j] = (m16 == head) ? (short)bhi16(Qlds[d]) : (short)0;
        }
    }
    float dn = 0.f, gs = 0.f;
    BARRIER();       // all waves done reading Wl/Qlds; E_lds may now overwrite

#define SLAB(s) do {                                                             \
        f32x4 c1 = {0.f, 0.f, 0.f, 0.f}, c2 = {0.f, 0.f, 0.f, 0.f};             \
        _Pragma("unroll")                                                        \
        for (int c = 0; c < 2; ++c) {                                            \
            const int g0 = c * 8 + a2 * 2;                                       \
            const float4 e0 = *(const float4*)&ebuf[w][m16][((g0 ^ m16) * 4)];   \
            const float4 e1 = *(const float4*)&ebuf[w][m16][(((g0 + 1) ^ m16) * 4)]; \
            bf16x8 ac;                                                           \
            ac[0] = (short)bhi16(e0.x); ac[1] = (short)bhi16(e0.y);              \
            ac[2] = (short)bhi16(e0.z); ac[3] = (short)bhi16(e0.w);              \
            ac[4] = (short)bhi16(e1.x); ac[5] = (short)bhi16(e1.y);              \
            ac[6] = (short)bhi16(e1.z); ac[7] = (short)bhi16(e1.w);              \
            c1 = __builtin_amdgcn_mfma_f32_16x16x32_bf16(ac, WB[c], c1, 0, 0, 0); \
            const bf16x8 kf = *(const bf16x8*)&kbl[w][m16]                       \
                                  [(((c * 4 + a2) ^ (m16 & 7)) * 8)];            \
            c2 = __builtin_amdgcn_mfma_f32_16x16x32_bf16(kf, QdB[c], c2, 0, 0, 0); \
        }                                                                        \
        if (m16 < 8) {                                                           \
            _Pragma("unroll")                                                    \
            for (int r = 0; r < 4; ++r) {                                        \
                const float E_ = fminf(fmaxf(c2[r] * SCALE, -5.f), 5.f) + c1[r]; \
                dn += __expf(E_ - SMAX);                                         \
                E_lds[w][(s) * 16 + a2 * 4 + r][m16] = E_;                       \
            }                                                                    \
        } else {                                                                 \
            _Pragma("unroll")                                                    \
            for (int r = 0; r < 4; ++r) gs += 1.f / (1.f + __expf(-c1[r]));      \
        } } while (0)

    WAITV(0);        // slab0 e+K landed
    SLAB(0);
    STAGE_E(1); STAGE_K(1);       // single buffer: reissue after slab0 reads
    WAITV(0);
    SLAB(1);

    // ---- reduce dn/gs across a2-groups ----
    dn += __shfl_xor(dn, 16, 64); dn += __shfl_xor(dn, 32, 64);
    gs += __shfl_xor(gs, 16, 64); gs += __shfl_xor(gs, 32, 64);
    if (a2 == 0 && m16 < 8) wdn[w][m16] = dn;
    if (a2 == 0 && m16 >= 8) wgs[w][m16 - 8] = gs;

    // ---- PV partial over own-wave 32 rows (256B/instr, L2-hot) ----
    {
        const int k = l & 7, hh = (l >> 3) & 7;
        const float* vb = qkv + (size_t)(b * NN + rowc) * 192 + 128 + hh * 8 + k;
        float acc = 0.f;
#pragma unroll 8
        for (int i = 0; i < 32; ++i) {
            const float p = __expf(E_lds[w][i][hh] - SMAX);
            acc = fmaf(p, vb[(size_t)i * 192], acc);
        }
        red[t] = acc;
    }
    __syncthreads();
    if (t < 64)
        pvw[(size_t)wg * 64 + t] = red[t] + red[64 + t] + red[128 + t] + red[192 + t];
    if (t < 8)
        dngs[(size_t)wg * 16 + t] = wdn[0][t] + wdn[1][t] + wdn[2][t] + wdn[3][t];
    else if (t < 16)
        dngs[(size_t)wg * 16 + t] = wgs[0][t - 8] + wgs[1][t - 8] + wgs[2][t - 8] + wgs[3][t - 8];

    // ---- e_out epilogue from E_lds; Oe coefficients from LDS ----
    {
        const int j4 = l & 15, mr = l >> 4;
        float oc[8][4];
#pragma unroll
        for (int h = 0; h < 8; ++h) {
            const float4 v = *(const float4*)&Oelds[h * 64 + j4 * 4];
            oc[h][0] = v.x; oc[h][1] = v.y; oc[h][2] = v.z; oc[h][3] = v.w;
        }
#pragma unroll 2
        for (int p = 0; p < 8; ++p) {
            const int mloc = p * 4 + mr;
            const float* er = &E_lds[w][mloc][0];
            const float4 ra = *reinterpret_cast<const float4*>(er);
            const float4 rb = *reinterpret_cast<const float4*>(er + 4);
            float o0 = ra.x * oc[0][0], o1 = ra.x * oc[0][1], o2 = ra.x * oc[0][2], o3 = ra.x * oc[0][3];
            o0 = fmaf(ra.y, oc[1][0], o0); o1 = fmaf(ra.y, oc[1][1], o1); o2 = fmaf(ra.y, oc[1][2], o2); o3 = fmaf(ra.y, oc[1][3], o3);
            o0 = fmaf(ra.z, oc[2][0], o0); o1 = fmaf(ra.z, oc[2][1], o1); o2 = fmaf(ra.z, oc[2][2], o2); o3 = fmaf(ra.z, oc[2][3], o3);
            o0 = fmaf(ra.w, oc[3][0], o0); o1 = fmaf(ra.w, oc[3][1], o1); o2 = fmaf(ra.w, oc[3][2], o2); o3 = fmaf(ra.w, oc[3][3], o3);
            o0 = fmaf(rb.x, oc[4][0], o0); o1 = fmaf(rb.x, oc[4][1], o1); o2 = fmaf(rb.x, oc[4][2], o2); o3 = fmaf(rb.x, oc[4][3], o3);
            o0 = fmaf(rb.y, oc[5][0], o0); o1 = fmaf(rb.y, oc[5][1], o1); o2 = fmaf(rb.y, oc[5][2], o2); o3 = fmaf(rb.y, oc[5][3], o3);
            o0 = fmaf(rb.z, oc[6][0], o0); o1 = fmaf(rb.z, oc[6][1], o1); o2 = fmaf(rb.z, oc[6][2], o2); o3 = fmaf(rb.z, oc[6][3], o3);
            o0 = fmaf(rb.w, oc[7][0], o0); o1 = fmaf(rb.w, oc[7][1], o1); o2 = fmaf(rb.w, oc[7][2], o2); o3 = fmaf(rb.w, oc[7][3], o3);
            reinterpret_cast<float4*>(eob + (size_t)(rowc + mloc) * 64 + j4 * 4)[0]
                = make_float4(o0, o1, o2, o3);
        }
    }
#undef STAGE_E
#undef STAGE_K
#undef SLAB
}

// ---------------- K3: combine partials -> n_out ----------------
__global__ __launch_bounds__(64) void nout_fin(
    const float* __restrict__ pvw,   // (8192,64)
    const float* __restrict__ dngs,  // (8192,16)
    const float* __restrict__ On,    // (64,64)
    float* __restrict__ n_out)       // (B,N,64)
{
    __shared__ float vfin[64];
    const int bn = blockIdx.x, t = threadIdx.x;
    const int hh = t >> 3;
    float pv = 0.f, den = 0.f, gsum = 0.f;
#pragma unroll
    for (int c = 0; c < 4; ++c) {
        const size_t wg = (size_t)bn * 4 + c;
        pv += pvw[wg * 64 + t];
        den += dngs[wg * 16 + hh];
        gsum += dngs[wg * 16 + 8 + hh];
    }
    vfin[t] = pv * (1.f / den) * log1pf(gsum);
    __syncthreads();
    float acc = 0.f;
#pragma unroll
    for (int i = 0; i < 64; ++i)
        acc = fmaf(vfin[i], On[i * 64 + t], acc);
    n_out[(size_t)bn * 64 + t] = acc;
}

extern "C" void kernel_launch(void* const* d_in, const int* in_sizes, int n_in,
                              void* d_out, int out_size, void* d_ws, size_t ws_size,
                              hipStream_t stream) {
    const float* n_in_p = (const float*)d_in[0];
    const float* e_p    = (const float*)d_in[1];
    const float* Wqkv   = (const float*)d_in[2];
    const float* On     = (const float*)d_in[3];
    const float* Wg     = (const float*)d_in[4];
    const float* We     = (const float*)d_in[5];
    const float* Oe     = (const float*)d_in[6];
    float* out = (float*)d_out;
    float* n_out = out;                              // 4*512*64
    float* e_out = out + (size_t)4 * 512 * 64;       // 4*512*512*64
    float* qkv = (float*)d_ws;                       // 393216 floats
    float* pvw = qkv + 393216;                       // 524288 floats
    float* dngs = pvw + 524288;                      // 131072 floats
    unsigned short* kbf = (unsigned short*)(dngs + 131072);  // 131072 ushorts

    hipLaunchKernelGGL(qkv_proj, dim3(4 * NN), dim3(64), 0, stream, n_in_p, Wqkv, qkv, kbf);
    hipLaunchKernelGGL(edge_mfma7, dim3(8192), dim3(256), 0, stream,
                       e_p, qkv, kbf, We, Wg, Oe, e_out, pvw, dngs);
    hipLaunchKernelGGL(nout_fin, dim3(4 * NN), dim3(64), 0, stream,
                       pvw, dngs, On, n_out);
}